// Round 9
// baseline (428.974 us; speedup 1.0000x reference)
//
#include <hip/hip_runtime.h>
#include <math.h>

// MAM fully-connected: out[r][o] = max_k(x[r][k]*W[o][k]) + min_k(x[r][k]*W[o][k]) + b[o]
// x: (1024, 512) f32, W: (512, 512) f32, b: (512,), out: (1024, 512) f32.
//
// v9 = R7-class (best, 21.2us) refined on all three modeled pipes:
//  - lane = out, j-outer/r-inner (liveness-1 W reuse: the only register-reuse
//    shape this compiler honors; R6/R8 proved it won't hold big fragments)
//  - K-split 4: each wave owns a K-quarter, all share the block's 8 rows ->
//    one ds_read_b128 feeds 8 rows; W DS reads halve vs R7 (512/CU)
//  - pk_mul: 1.5 VALU-ops/product (VALU floor 5.1us); now visible since DS is decongested
//  - padded LDS row stride = 20 words: ds_write AND ds_read are exactly
//    8 words/bank (verified: 20*o mod 32 spans all 8 multiples-of-4 x 16-word
//    windows uniformly) -> structural optimum, no XOR
//  - reg-staged staging (padded dest forbids global_load_lds): 4 coalesced
//    16-full-line loads issued BEFORE compute, ds_writes after (vmcnt hidden)
//  - 1024 blocks, 40KB LDS -> 4 blocks/CU, 4 waves/SIMD; 1 barrier/phase
//  - merge: 4 K-quarters combined via 16KB buffer aliased into Wl[0]

#define O_TOTAL 512
#define K_TOTAL 512
#define OBLK 64
#define RPB 8                    // rows per block (shared by all 4 waves)
#define KQ 128                   // K per quarter (per wave)
#define KPH 16                   // K per phase per quarter
#define NPH (KQ / KPH)           // 8 phases
#define STRIDE 20                // padded LDS row stride (floats)
#define QSTRIDE (OBLK * STRIDE)  // 1280 floats per quarter strip
#define BUFSZ (4 * QSTRIDE)      // 5120 floats per phase buffer (20 KB)

typedef float f32x2 __attribute__((ext_vector_type(2)));

__device__ __forceinline__ f32x2 pk_mul(f32x2 a, f32x2 b) {
  f32x2 d;
  asm("v_pk_mul_f32 %0, %1, %2" : "=v"(d) : "v"(a), "v"(b));
  return d;
}

__global__ __launch_bounds__(256, 4)
void mam_fc_kernel(const float* __restrict__ x, const float* __restrict__ W,
                   const float* __restrict__ bias, float* __restrict__ out) {
  __shared__ __align__(16) float Wl[2][BUFSZ];   // 40 KB total

  const int t = threadIdx.x;
  const int lane = t & 63;
  const int q = __builtin_amdgcn_readfirstlane(t >> 6);   // K-quarter owner
  const int ob = blockIdx.x & 7;        // 8 out-blocks of 64
  const int rg = blockIdx.x >> 3;       // 128 row-groups of 8
  const int o0 = ob * OBLK;
  const int row0 = rg * RPB;

  // staging map: thread t covers out o_s = t>>2, 16B granule g_s = t&3, for all
  // 4 quarters. Global side: 64B-aligned 64B runs from 16 rows per wave-instr
  // = 16 FULL cache lines (perfectly efficient). LDS side: stride-20 rows ->
  // uniform 8 words/bank on ds_write_b128.
  const int o_s = t >> 2, g_s = t & 3;
  const float* srcW = W + (size_t)(o0 + o_s) * K_TOTAL + g_s * 4;
  const int dstW = o_s * STRIDE + g_s * 4;

  const float* xq = x + (size_t)row0 * K_TOTAL + q * KQ;   // wave-uniform

  float amax[RPB], amin[RPB];
#pragma unroll
  for (int r = 0; r < RPB; ++r) { amax[r] = -INFINITY; amin[r] = INFINITY; }

  // prologue: stage phase 0 into buf 0
  {
    float4 stg[4];
#pragma unroll
    for (int qq = 0; qq < 4; ++qq)
      stg[qq] = *reinterpret_cast<const float4*>(srcW + qq * KQ);
#pragma unroll
    for (int qq = 0; qq < 4; ++qq)
      *reinterpret_cast<float4*>(&Wl[0][qq * QSTRIDE + dstW]) = stg[qq];
  }

#pragma unroll
  for (int ph = 0; ph < NPH; ++ph) {
    __syncthreads();   // buf[ph&1] ready; everyone done reading buf[(ph+1)&1]

    // issue next-phase global loads FIRST (latency hides under compute)
    float4 stg[4];
    if (ph + 1 < NPH) {
#pragma unroll
      for (int qq = 0; qq < 4; ++qq)
        stg[qq] = *reinterpret_cast<const float4*>(srcW + qq * KQ + (ph + 1) * KPH);
    }

    // compute: this wave's K-quarter, phase slice; w4 liveness-1, feeds 8 rows
    const float* wq = &Wl[ph & 1][q * QSTRIDE + lane * STRIDE];
    const float* xp = xq + ph * KPH;
#pragma unroll
    for (int j = 0; j < KPH / 4; ++j) {
      const float4 w4 = *reinterpret_cast<const float4*>(wq + j * 4);  // 8 w/bank
#pragma unroll
      for (int r = 0; r < RPB; ++r) {
        const float4 xv = *reinterpret_cast<const float4*>(xp + r * K_TOTAL + j * 4);
        const f32x2 a = pk_mul(f32x2{xv.x, xv.y}, f32x2{w4.x, w4.y});
        const f32x2 b = pk_mul(f32x2{xv.z, xv.w}, f32x2{w4.z, w4.w});
        // each pair folds to one v_max3/v_min3: 6 slots per 4 products
        amax[r] = fmaxf(fmaxf(amax[r], a.x), a.y);
        amin[r] = fminf(fminf(amin[r], a.x), a.y);
        amax[r] = fmaxf(fmaxf(amax[r], b.x), b.y);
        amin[r] = fminf(fminf(amin[r], b.x), b.y);
      }
    }

    // write staged data into the other buffer (vmcnt wait already covered)
    if (ph + 1 < NPH) {
#pragma unroll
      for (int qq = 0; qq < 4; ++qq)
        *reinterpret_cast<float4*>(&Wl[(ph + 1) & 1][qq * QSTRIDE + dstW]) = stg[qq];
    }
  }

  // ---- K-quarter merge via 16 KB buffer aliased into Wl[0] (free: last phase
  // read Wl[1]; all Wl[0] reads completed before the ph=7 barrier) ----
  float* red = &Wl[0][0];   // [q][r][lane] pairs: q*1024 + r*128 + lane*2
#pragma unroll
  for (int r = 0; r < RPB; ++r)
    *reinterpret_cast<f32x2*>(&red[q * 1024 + r * 128 + lane * 2]) =
        f32x2{amax[r], amin[r]};
  __syncthreads();

  const float bv = bias[o0 + lane];
#pragma unroll
  for (int i = 0; i < 2; ++i) {           // wave q finalizes rows 2q, 2q+1
    const int r = q * 2 + i;
    float m = -INFINITY, n = INFINITY;
#pragma unroll
    for (int qq = 0; qq < 4; ++qq) {
      const f32x2 v = *reinterpret_cast<const f32x2*>(&red[qq * 1024 + r * 128 + lane * 2]);
      m = fmaxf(m, v.x);
      n = fminf(n, v.y);
    }
    out[(size_t)(row0 + r) * O_TOTAL + o0 + lane] = m + n + bv;   // coalesced
  }
}

extern "C" void kernel_launch(void* const* d_in, const int* in_sizes, int n_in,
                              void* d_out, int out_size, void* d_ws, size_t ws_size,
                              hipStream_t stream) {
  const float* x = (const float*)d_in[0];    // (1024, 512)
  const float* W = (const float*)d_in[1];    // (512, 512)
  const float* b = (const float*)d_in[2];    // (512,)
  float* out = (float*)d_out;                // (1024, 512)

  const int nrows = in_sizes[0] / K_TOTAL;                 // 1024
  const int nblocks = (O_TOTAL / OBLK) * (nrows / RPB);    // 8 * 128 = 1024
  mam_fc_kernel<<<dim3(nblocks), dim3(256), 0, stream>>>(x, W, b, out);
}

// Round 10
// 28.825 us; speedup vs baseline: 14.8818x; 14.8818x over previous
//
#include <hip/hip_runtime.h>
#include <math.h>

// MAM fully-connected: out[r][o] = max_k(x[r][k]*W[o][k]) + min_k(x[r][k]*W[o][k]) + b[o]
// v10 (final): R7 skeleton + K-split-4 + pk_mul; XOR source-swizzle s(o)=(o>>1)&3;
// global_load_lds staging; phase loop not unrolled; merge aliased into buf0.

#define O_TOTAL 512
#define K_TOTAL 512
#define OBLK 64
#define RPB 8
#define KQ 128
#define KPH 16
#define NPH (KQ / KPH)
#define PHW (4 * OBLK * KPH)

typedef float f32x2 __attribute__((ext_vector_type(2)));

__device__ __forceinline__ f32x2 pk_mul(f32x2 a, f32x2 b) {
  f32x2 d;
  asm("v_pk_mul_f32 %0, %1, %2" : "=v"(d) : "v"(a), "v"(b));
  return d;
}

__device__ __forceinline__ void stage16(const float* g, float* lds_base) {
#if __has_builtin(__builtin_amdgcn_global_load_lds)
  __builtin_amdgcn_global_load_lds(
      (__attribute__((address_space(1))) unsigned int*)g,
      (__attribute__((address_space(3))) unsigned int*)lds_base, 16, 0, 0);
#else
  *reinterpret_cast<float4*>(lds_base + (threadIdx.x & 63) * 4) =
      *reinterpret_cast<const float4*>(g);
#endif
}

__global__ __launch_bounds__(256, 4)
void mam_fc_kernel(const float* __restrict__ x, const float* __restrict__ W,
                   const float* __restrict__ bias, float* __restrict__ out) {
  __shared__ __align__(16) float smem[2][PHW];   // 32 KB

  const int t = threadIdx.x;
  const int lane = t & 63;
  const int q = __builtin_amdgcn_readfirstlane(t >> 6);
  const int ob = blockIdx.x & 7;
  const int rg = blockIdx.x >> 3;
  const int o0 = ob * OBLK;
  const int row0 = rg * RPB;

  const float* srcW[4];
  int dstOff[4];
#pragma unroll
  for (int i = 0; i < 4; ++i) {
    const int o = i * 16 + (lane >> 2);
    const int gl = (lane & 3) ^ ((o >> 1) & 3);
    srcW[i] = W + (size_t)(o0 + o) * K_TOTAL + q * KQ + gl * 4;
    dstOff[i] = (q * 4 + i) * 256;
  }

  const float* xq = x + (size_t)row0 * K_TOTAL + q * KQ;

  float amax[RPB], amin[RPB];
#pragma unroll
  for (int r = 0; r < RPB; ++r) { amax[r] = -INFINITY; amin[r] = INFINITY; }

  const unsigned baseW =
      (unsigned)(q * 4096 + lane * 64 + ((lane >> 1) & 3) * 16);

#pragma unroll
  for (int i = 0; i < 4; ++i) stage16(srcW[i], &smem[0][dstOff[i]]);

#pragma unroll 1
  for (int ph = 0; ph < NPH; ++ph) {
    __syncthreads();

    if (ph + 1 < NPH) {
#pragma unroll
      for (int i = 0; i < 4; ++i)
        stage16(srcW[i] + (ph + 1) * KPH, &smem[(ph + 1) & 1][dstOff[i]]);
    }

    const char* wb = (const char*)&smem[ph & 1][0];
    const float* xp = xq + ph * KPH;
#pragma unroll
    for (int j = 0; j < KPH / 4; ++j) {
      const float4 w4 =
          *reinterpret_cast<const float4*>(wb + (baseW ^ (unsigned)(j * 16)));
#pragma unroll
      for (int r = 0; r < RPB; ++r) {
        const float4 xv =
            *reinterpret_cast<const float4*>(xp + r * K_TOTAL + j * 4);
        const f32x2 a = pk_mul(f32x2{xv.x, xv.y}, f32x2{w4.x, w4.y});
        const f32x2 b = pk_mul(f32x2{xv.z, xv.w}, f32x2{w4.z, w4.w});
        amax[r] = fmaxf(fmaxf(amax[r], a.x), a.y);
        amin[r] = fminf(fminf(amin[r], a.x), a.y);
        amax[r] = fmaxf(fmaxf(amax[r], b.x), b.y);
        amin[r] = fminf(fminf(amin[r], b.x), b.y);
      }
    }
  }

  float* red = &smem[0][0];
#pragma unroll
  for (int r = 0; r < RPB; ++r)
    *reinterpret_cast<f32x2*>(&red[q * 1024 + r * 128 + lane * 2]) =
        f32x2{amax[r], amin[r]};
  __syncthreads();

  const float bv = bias[o0 + lane];
#pragma unroll
  for (int i = 0; i < 2; ++i) {
    const int r = q * 2 + i;
    float m = -INFINITY, n = INFINITY;
#pragma unroll
    for (int qq = 0; qq < 4; ++qq) {
      const f32x2 v =
          *reinterpret_cast<const f32x2*>(&red[qq * 1024 + r * 128 + lane * 2]);
      m = fmaxf(m, v.x);
      n = fminf(n, v.y);
    }
    out[(size_t)(row0 + r) * O_TOTAL + o0 + lane] = m + n + bv;
  }
}

extern "C" void kernel_launch(void* const* d_in, const int* in_sizes, int n_in,
                              void* d_out, int out_size, void* d_ws, size_t ws_size,
                              hipStream_t stream) {
  const float* x = (const float*)d_in[0];
  const float* W = (const float*)d_in[1];
  const float* b = (const float*)d_in[2];
  float* out = (float*)d_out;

  const int nrows = in_sizes[0] / K_TOTAL;                 // 1024
  const int nblocks = (O_TOTAL / OBLK) * (nrows / RPB);    // 1024
  mam_fc_kernel<<<dim3(nblocks), dim3(256), 0, stream>>>(x, W, b, out);
}